// Round 5
// baseline (1311.671 us; speedup 1.0000x reference)
//
#include <hip/hip_runtime.h>

// ---------------------------------------------------------------------------
// AttnBlock: GroupNorm -> q,k,v 1x1 conv -> softmax(QK^T/sqrt(C)) V -> out proj
// B=4, H=W=64 (4096 positions/batch), C=512, 32 groups.
// bf16 MFMA pipeline, fp32 accumulation. No-max softmax. XCD-aware remap
// (R2-verified: FETCH 90->41.5MB). V in registers (R4: LDS 69->37.9KB).
// R5: 4-way split-K flash -> grid 1024 -> 4 blocks/CU -> 16 waves/CU.
// Diagnosis: MFMA 21% / VALU 10% / LDS ~40% / HBM 4.5% -- nothing saturated;
// 10.3k cyc wall per iter vs ~2.5k cyc pipe work => latency/barrier-bound at
// 8 waves/CU. TLP is the binding constraint; 4 blocks/CU fits only with
// R4's V-in-reg LDS footprint (4 x 37.9KB <= 160KB, VGPR=128 = 4 waves/SIMD).
// Workspace-guarded: needs ~117MB for 4 O-partials; falls back to 2-way.
// ---------------------------------------------------------------------------

typedef __attribute__((ext_vector_type(8))) __bf16 bf16x8;
typedef __attribute__((ext_vector_type(4))) __bf16 bf16x4;
typedef __attribute__((ext_vector_type(4))) float  floatx4;

#define C_DIM 512
#define SPB   4096
#define MTOT  16384

// workspace layout (bytes).
// 2-way path (peak ~84.4 MiB): as before.
// 4-way path (peak ~116.5 MiB): op2/op3 appended, lpart/gstats moved up.
#define HN_OFF  ((size_t)0)            // hn bf16 [16384][512]; reused as Opart0
#define Q_OFF   ((size_t)16 << 20)     // q bf16 (pre-scaled); reused as attn
#define K_OFF   ((size_t)32 << 20)     // k bf16
#define V4_OFF  ((size_t)48 << 20)     // v bf16 grouped [B][512 pg][512 ch][8key]
#define WT_OFF  ((size_t)64 << 20)     // wT bf16 [4][512 out][512 in]
#define O1_OFF  ((size_t)68 << 20)     // Opart1 bf16 [16384][512]
#define ML_OFF  ((size_t)84 << 20)     // 2-way: lpart fp32 [2][16384]
#define GS_OFF  (ML_OFF + (size_t)(256 << 10))
#define O2_OFF  ((size_t)84 << 20)     // 4-way: Opart2
#define O3_OFF  ((size_t)100 << 20)    // 4-way: Opart3
#define ML4_OFF ((size_t)116 << 20)    // 4-way: lpart fp32 [4][16384]
#define GS4_OFF (ML4_OFF + (size_t)(256 << 10))
#define NEED4   (GS4_OFF + (size_t)(64 << 10))

__device__ inline floatx4 mfma16(bf16x8 a, bf16x8 b, floatx4 c) {
    return __builtin_amdgcn_mfma_f32_16x16x32_bf16(a, b, c, 0, 0, 0);
}

__device__ inline void gload16(const void* g, void* lds) {
    __builtin_amdgcn_global_load_lds(
        (const __attribute__((address_space(1))) unsigned int*)g,
        (__attribute__((address_space(3))) unsigned int*)lds, 16, 0, 0);
}

// ---------------------------------------------------------------------------
// GroupNorm stats: grid (128, 4) - block = (batch,group) x spatial quarter.
// ---------------------------------------------------------------------------
__global__ __launch_bounds__(256) void zero_stats(float* gstats) {
    gstats[threadIdx.x] = 0.f;
}

__global__ __launch_bounds__(256) void gn_stats(
    const float* __restrict__ x, float* __restrict__ gstats) {
    int bg = blockIdx.x;                    // b*32+g
    int b = bg >> 5, g = bg & 31;
    int tid = threadIdx.x;
    int cq = tid & 3, s0 = tid >> 2;
    const float* base = x + (size_t)b * SPB * C_DIM + g * 16 + cq * 4
                          + (size_t)blockIdx.y * 1024 * C_DIM;
    float sum = 0.f, sq = 0.f;
#pragma unroll 4
    for (int i = 0; i < 16; ++i) {
        floatx4 v = *(const floatx4*)(base + (size_t)(i * 64 + s0) * C_DIM);
        sum += v[0] + v[1] + v[2] + v[3];
        sq  += v[0]*v[0] + v[1]*v[1] + v[2]*v[2] + v[3]*v[3];
    }
#pragma unroll
    for (int off = 1; off < 64; off <<= 1) {
        sum += __shfl_xor(sum, off);
        sq  += __shfl_xor(sq,  off);
    }
    __shared__ float sm[8];
    int w = tid >> 6, lane = tid & 63;
    if (lane == 0) { sm[w] = sum; sm[4 + w] = sq; }
    __syncthreads();
    if (tid == 0) {
        atomicAdd(&gstats[bg * 2],     sm[0] + sm[1] + sm[2] + sm[3]);
        atomicAdd(&gstats[bg * 2 + 1], sm[4] + sm[5] + sm[6] + sm[7]);
    }
}

__global__ __launch_bounds__(256) void gn_apply(
    const float* __restrict__ x, const float* __restrict__ gstats,
    const float* __restrict__ gsc, const float* __restrict__ gbi,
    __bf16* __restrict__ hn) {
    int bg = blockIdx.x;
    int b = bg >> 5, g = bg & 31;
    int tid = threadIdx.x;
    int cq = tid & 3, s0 = tid >> 2;
    float S  = gstats[bg * 2], Qs = gstats[bg * 2 + 1];
    float mean = S * (1.f / 65536.f);
    float var  = Qs * (1.f / 65536.f) - mean * mean;
    float rstd = rsqrtf(var + 1e-6f);
    float sc[4], bi[4];
#pragma unroll
    for (int j = 0; j < 4; ++j) {
        float s_ = gsc[g * 16 + cq * 4 + j] * rstd;
        sc[j] = s_;
        bi[j] = gbi[g * 16 + cq * 4 + j] - mean * s_;
    }
    size_t off = (size_t)b * SPB * C_DIM + g * 16 + cq * 4
               + (size_t)blockIdx.y * 1024 * C_DIM;
    const float* base = x + off;
    __bf16* hbase = hn + off;
#pragma unroll 4
    for (int i = 0; i < 16; ++i) {
        floatx4 v = *(const floatx4*)(base + (size_t)(i * 64 + s0) * C_DIM);
        bf16x4 o;
#pragma unroll
        for (int j = 0; j < 4; ++j) o[j] = (__bf16)(v[j] * sc[j] + bi[j]);
        *(bf16x4*)(hbase + (size_t)(i * 64 + s0) * C_DIM) = o;
    }
}

// ---------------------------------------------------------------------------
// Weight transpose + bf16 convert: wT[z][n][k] = w_z[k][n]
// ---------------------------------------------------------------------------
__global__ __launch_bounds__(256) void wt_kernel(
    const float* __restrict__ w0, const float* __restrict__ w1,
    const float* __restrict__ w2, const float* __restrict__ w3,
    __bf16* __restrict__ wt) {
    const float* srcs[4] = {w0, w1, w2, w3};
    const float* src = srcs[blockIdx.z];
    __bf16* dst = wt + (size_t)blockIdx.z * C_DIM * C_DIM;
    __shared__ float tile[32][33];
    int tx = threadIdx.x & 31, ty = threadIdx.x >> 5;
    int gx = blockIdx.x * 32, gy = blockIdx.y * 32;
#pragma unroll
    for (int i = 0; i < 4; ++i)
        tile[ty + i * 8][tx] = src[(size_t)(gy + ty + i * 8) * C_DIM + gx + tx];
    __syncthreads();
#pragma unroll
    for (int i = 0; i < 4; ++i) {
        int n = gx + ty + i * 8;
        int k = gy + tx;
        dst[(size_t)n * C_DIM + k] = (__bf16)tile[tx][ty + i * 8];
    }
}

// ---------------------------------------------------------------------------
// q/k/v projection GEMM: 128x128 tile, BK=32, async LDS staging.
// ---------------------------------------------------------------------------
__global__ __launch_bounds__(256, 2) void proj_qkv(
    const __bf16* __restrict__ hn, const __bf16* __restrict__ wt_all,
    const float* __restrict__ bq, const float* __restrict__ bk,
    const float* __restrict__ bv, __bf16* __restrict__ qout,
    __bf16* __restrict__ kout, __bf16* __restrict__ v4out) {
    int z = blockIdx.z;
    const __bf16* wt = wt_all + (size_t)z * C_DIM * C_DIM;
    const float* bias = (z == 0) ? bq : (z == 1) ? bk : bv;
    __shared__ __bf16 Alds[128 * 32];
    __shared__ __bf16 Blds[128 * 32];
    int tid = threadIdx.x, lane = tid & 63, w = tid >> 6;
    int c = lane & 15, quad = lane >> 4;
    int wm = w & 1, wn = w >> 1;
    int mbase = blockIdx.x * 128, nbase = blockIdx.y * 128;
    floatx4 acc[4][4] = {};
    for (int kb = 0; kb < 16; ++kb) {
        __syncthreads();
#pragma unroll
        for (int p = 0; p < 2; ++p) {
            int chunk0 = w * 128 + p * 64;
            int chunk = chunk0 + lane;
            int row = chunk >> 2, qk = chunk & 3;
            gload16(hn + (size_t)(mbase + row) * C_DIM + kb * 32 + qk * 8, Alds + chunk0 * 8);
            gload16(wt + (size_t)(nbase + row) * C_DIM + kb * 32 + qk * 8, Blds + chunk0 * 8);
        }
        __syncthreads();
        bf16x8 af[4], bfr[4];
#pragma unroll
        for (int mt = 0; mt < 4; ++mt)
            af[mt] = *(const bf16x8*)(Alds + (wm * 64 + mt * 16 + c) * 32 + quad * 8);
#pragma unroll
        for (int nt = 0; nt < 4; ++nt)
            bfr[nt] = *(const bf16x8*)(Blds + (wn * 64 + nt * 16 + c) * 32 + quad * 8);
#pragma unroll
        for (int mt = 0; mt < 4; ++mt)
#pragma unroll
            for (int nt = 0; nt < 4; ++nt)
                acc[mt][nt] = mfma16(af[mt], bfr[nt], acc[mt][nt]);
    }
    float scale = (z == 0) ? 0.0441941738241592f : 1.0f;   // 512^-0.5
#pragma unroll
    for (int nt = 0; nt < 4; ++nt) {
        int n = nbase + wn * 64 + nt * 16 + c;
        float bval = bias[n];
#pragma unroll
        for (int mt = 0; mt < 4; ++mt) {
            int m0 = mbase + wm * 64 + mt * 16 + quad * 4;
#pragma unroll
            for (int r = 0; r < 4; ++r) {
                int m = m0 + r;
                float val = (acc[mt][nt][r] + bval) * scale;
                if (z == 0)      qout[(size_t)m * C_DIM + n] = (__bf16)val;
                else if (z == 1) kout[(size_t)m * C_DIM + n] = (__bf16)val;
                else {
                    int bb = m >> 12, pos = m & 4095;
                    v4out[((size_t)(bb * 512 + (pos >> 3)) * C_DIM + n) * 8 + (pos & 7)] = (__bf16)val;
                }
            }
        }
    }
}

// ---------------------------------------------------------------------------
// Split-K flash attention, templated on NS (key-range splits).
// NS=4: grid 1024 (4 blocks/CU, 16 waves/CU). decode: x=bid&7 is the XCD;
//       group g = x + 8*(i&1) in 0..15 -> (b = g>>2, h = g&3); qt = i>>1.
//       Groups g and g+8 share XCD x: K+V working set 2x(1+1)MB = 4MB L2-fit.
// NS=2: grid 512, R2/R4 decode (fallback when workspace < NEED4).
// Per iter: [V(kt) -> REGS] S-phase | softmax | P-write | barrier A
// [K(kt+1) -> LDS] PV (V from regs) | barrier C.
// ---------------------------------------------------------------------------
__device__ inline void stage_K(const __bf16* kbase, int key0,
                               __bf16* Klds, int w, int lane) {
#pragma unroll
    for (int p = 0; p < 8; ++p) {
        int chunk0 = w * 512 + p * 64;
        int chunk = chunk0 + lane;
        gload16(kbase + (size_t)(key0 + (chunk & 31)) * C_DIM + (chunk >> 5) * 8,
                Klds + chunk0 * 8);
    }
}

template <int NS>
__global__ __launch_bounds__(256, 4) void flash_kernel(
    const __bf16* __restrict__ q, const __bf16* __restrict__ kmat,
    const __bf16* __restrict__ v4, __bf16* __restrict__ op0,
    __bf16* __restrict__ op1, __bf16* __restrict__ op2,
    __bf16* __restrict__ op3, float* __restrict__ lpart) {
    __shared__ __bf16 Klds[16384];     // 32 KB: [cg 64][key 32][8ch]
    __shared__ __bf16 Plds[64 * 40];   // 5 KB : [row 64][key 32 + pad 8]
    int tid = threadIdx.x, lane = tid & 63, w = tid >> 6;
    int c = lane & 15, quad = lane >> 4;
    int bid = blockIdx.x;
    int b, h, qt;
    if constexpr (NS == 2) {
        int xcd = bid & 7;
        b = xcd >> 1; h = xcd & 1; qt = bid >> 3;
    } else {
        int x = bid & 7, i = bid >> 3;
        int g = x + 8 * (i & 1);           // 0..15
        b = g >> 2; h = g & 3; qt = i >> 1;
    }
    constexpr int KPS = 4096 / NS;         // keys per split
    constexpr int NIT = KPS / 32;          // iterations

    const __bf16* qp = q + ((size_t)(b * SPB + qt * 64 + w * 16 + c)) * C_DIM + quad * 8;
    bf16x8 qf[16];
#pragma unroll
    for (int ks = 0; ks < 16; ++ks) qf[ks] = *(const bf16x8*)(qp + ks * 32);
    floatx4 o[4][8];
#pragma unroll
    for (int mg = 0; mg < 4; ++mg)
#pragma unroll
        for (int t = 0; t < 8; ++t) o[mg][t] = (floatx4){0.f, 0.f, 0.f, 0.f};
    float l_r[4] = {0.f, 0.f, 0.f, 0.f};

    const __bf16* kbase = kmat + (size_t)b * SPB * C_DIM;
    const __bf16* vbase = v4 + (size_t)b * 512 * C_DIM * 8;

    stage_K(kbase, h * KPS, Klds, w, lane);    // prologue: K(0)
    __syncthreads();                           // drain: K(0) ready

    for (int kt = 0; kt < NIT; ++kt) {
        int key0 = h * KPS + kt * 32;
        // issue V(kt) -> registers; consumed in PV (~600+ cyc of cover).
        const __bf16* vp = vbase
            + ((size_t)((key0 >> 3) + quad) * C_DIM + w * 128 + c) * 8;
        bf16x8 vreg[8];
#pragma unroll
        for (int t = 0; t < 8; ++t)
            vreg[t] = *(const bf16x8*)(vp + (size_t)t * 16 * 8);
        // ---- S = Q K^T: 16 q-rows x 32 keys per wave (K(kt) in Klds) ----
        floatx4 s0 = (floatx4){0.f,0.f,0.f,0.f}, s1 = (floatx4){0.f,0.f,0.f,0.f};
#pragma unroll
        for (int ks = 0; ks < 16; ++ks) {
            bf16x8 k0 = *(const bf16x8*)(Klds + (((ks * 4 + quad) * 32) + c) * 8);
            bf16x8 k1 = *(const bf16x8*)(Klds + (((ks * 4 + quad) * 32) + c + 16) * 8);
            s0 = mfma16(qf[ks], k0, s0);
            s1 = mfma16(qf[ks], k1, s1);
        }
        // ---- no-max softmax: p = exp(s), accumulate l per-lane ----
#pragma unroll
        for (int r = 0; r < 4; ++r) {
            float p0 = __expf(s0[r]);
            float p1 = __expf(s1[r]);
            l_r[r] += p0 + p1;
            int row = w * 16 + quad * 4 + r;
            Plds[row * 40 + c]      = (__bf16)p0;
            Plds[row * 40 + c + 16] = (__bf16)p1;
        }
        __syncthreads();   // A: P visible; Klds reads done
        // issue K(kt+1): latency covered by PV phase
        int kn = (kt < NIT - 1) ? kt + 1 : NIT - 1;
        stage_K(kbase, h * KPS + kn * 32, Klds, w, lane);
        // ---- O += P V (channel-split: all 64 rows, chans w*128..) ----
        bf16x8 pf[4];
#pragma unroll
        for (int mg = 0; mg < 4; ++mg)
            pf[mg] = *(const bf16x8*)(Plds + (mg * 16 + c) * 40 + quad * 8);
#pragma unroll
        for (int t = 0; t < 8; ++t) {
#pragma unroll
            for (int mg = 0; mg < 4; ++mg)
                o[mg][t] = mfma16(pf[mg], vreg[t], o[mg][t]);
        }
        __syncthreads();   // C: PV P-reads done; K(kt+1) drained
    }
    // ---- epilogue: reduce l across the 16 lanes sharing each row ----
#pragma unroll
    for (int r = 0; r < 4; ++r) {
        float l = l_r[r];
        l += __shfl_xor(l, 1);
        l += __shfl_xor(l, 2);
        l += __shfl_xor(l, 4);
        l += __shfl_xor(l, 8);
        l_r[r] = l;
    }
    if (c == 0) {
#pragma unroll
        for (int r = 0; r < 4; ++r) {
            int grow = b * SPB + qt * 64 + w * 16 + quad * 4 + r;
            lpart[h * MTOT + grow] = l_r[r];
        }
    }
    __bf16* ob;
    if constexpr (NS == 2) ob = h ? op1 : op0;
    else ob = (h == 0) ? op0 : (h == 1) ? op1 : (h == 2) ? op2 : op3;
#pragma unroll
    for (int mg = 0; mg < 4; ++mg)
#pragma unroll
        for (int t = 0; t < 8; ++t)
#pragma unroll
            for (int r = 0; r < 4; ++r) {
                int grow = b * SPB + qt * 64 + mg * 16 + quad * 4 + r;
                ob[(size_t)grow * C_DIM + w * 128 + t * 16 + c] = (__bf16)o[mg][t][r];
            }
}

// ---------------------------------------------------------------------------
// Combine key-range partials: attn = (sum O_s) / (sum l_s)
// ---------------------------------------------------------------------------
template <int NS>
__global__ __launch_bounds__(256) void combine_kernel(
    const __bf16* __restrict__ o0, const __bf16* __restrict__ o1,
    const __bf16* __restrict__ o2, const __bf16* __restrict__ o3,
    const float* __restrict__ lpart, __bf16* __restrict__ attn) {
    int tid = threadIdx.x, lane = tid & 63, w = tid >> 6;
    int rbase = blockIdx.x * 64 + w * 16;
    for (int rr = 0; rr < 16; ++rr) {
        int row = rbase + rr;
        float lsum = lpart[row] + lpart[MTOT + row];
        if constexpr (NS == 4)
            lsum += lpart[2 * MTOT + row] + lpart[3 * MTOT + row];
        float inv = 1.f / lsum;
        bf16x8 v0 = *(const bf16x8*)(o0 + (size_t)row * C_DIM + lane * 8);
        bf16x8 v1 = *(const bf16x8*)(o1 + (size_t)row * C_DIM + lane * 8);
        bf16x8 r;
        if constexpr (NS == 4) {
            bf16x8 v2 = *(const bf16x8*)(o2 + (size_t)row * C_DIM + lane * 8);
            bf16x8 v3 = *(const bf16x8*)(o3 + (size_t)row * C_DIM + lane * 8);
#pragma unroll
            for (int j = 0; j < 8; ++j)
                r[j] = (__bf16)((((float)v0[j] + (float)v1[j]) +
                                 ((float)v2[j] + (float)v3[j])) * inv);
        } else {
#pragma unroll
            for (int j = 0; j < 8; ++j)
                r[j] = (__bf16)(((float)v0[j] + (float)v1[j]) * inv);
        }
        *(bf16x8*)(attn + (size_t)row * C_DIM + lane * 8) = r;
    }
}

// ---------------------------------------------------------------------------
// out = x + attn @ wo + bo (fp32 output)
// ---------------------------------------------------------------------------
__global__ __launch_bounds__(256, 2) void proj_out(
    const __bf16* __restrict__ attn, const __bf16* __restrict__ wot,
    const float* __restrict__ bo, const float* __restrict__ x,
    float* __restrict__ out) {
    __shared__ __bf16 Alds[128 * 32];
    __shared__ __bf16 Blds[128 * 32];
    int tid = threadIdx.x, lane = tid & 63, w = tid >> 6;
    int c = lane & 15, quad = lane >> 4;
    int wm = w & 1, wn = w >> 1;
    int mbase = blockIdx.x * 128, nbase = blockIdx.y * 128;
    floatx4 acc[4][4] = {};
    for (int kb = 0; kb < 16; ++kb) {
        __syncthreads();
#pragma unroll
        for (int p = 0; p < 2; ++p) {
            int chunk0 = w * 128 + p * 64;
            int chunk = chunk0 + lane;
            int row = chunk >> 2, qk = chunk & 3;
            gload16(attn + (size_t)(mbase + row) * C_DIM + kb * 32 + qk * 8, Alds + chunk0 * 8);
            gload16(wot + (size_t)(nbase + row) * C_DIM + kb * 32 + qk * 8, Blds + chunk0 * 8);
        }
        __syncthreads();
        bf16x8 af[4], bfr[4];
#pragma unroll
        for (int mt = 0; mt < 4; ++mt)
            af[mt] = *(const bf16x8*)(Alds + (wm * 64 + mt * 16 + c) * 32 + quad * 8);
#pragma unroll
        for (int nt = 0; nt < 4; ++nt)
            bfr[nt] = *(const bf16x8*)(Blds + (wn * 64 + nt * 16 + c) * 32 + quad * 8);
#pragma unroll
        for (int mt = 0; mt < 4; ++mt)
#pragma unroll
            for (int nt = 0; nt < 4; ++nt)
                acc[mt][nt] = mfma16(af[mt], bfr[nt], acc[mt][nt]);
    }
#pragma unroll
    for (int nt = 0; nt < 4; ++nt) {
        int n = nbase + wn * 64 + nt * 16 + c;
        float bval = bo[n];
#pragma unroll
        for (int mt = 0; mt < 4; ++mt) {
            int m0 = mbase + wm * 64 + mt * 16 + quad * 4;
#pragma unroll
            for (int r = 0; r < 4; ++r) {
                size_t idx = (size_t)(m0 + r) * C_DIM + n;
                out[idx] = acc[mt][nt][r] + bval + x[idx];
            }
        }
    }
}

// ---------------------------------------------------------------------------
extern "C" void kernel_launch(void* const* d_in, const int* in_sizes, int n_in,
                              void* d_out, int out_size, void* d_ws, size_t ws_size,
                              hipStream_t stream) {
    const float* x   = (const float*)d_in[0];
    const float* gsc = (const float*)d_in[1];
    const float* gbi = (const float*)d_in[2];
    const float* wq  = (const float*)d_in[3];
    const float* bq  = (const float*)d_in[4];
    const float* wk  = (const float*)d_in[5];
    const float* bk  = (const float*)d_in[6];
    const float* wv  = (const float*)d_in[7];
    const float* bv  = (const float*)d_in[8];
    const float* wo  = (const float*)d_in[9];
    const float* bo  = (const float*)d_in[10];
    char* ws = (char*)d_ws;
    __bf16* hn  = (__bf16*)(ws + HN_OFF);
    __bf16* qb  = (__bf16*)(ws + Q_OFF);
    __bf16* kb  = (__bf16*)(ws + K_OFF);
    __bf16* v4  = (__bf16*)(ws + V4_OFF);
    __bf16* wt  = (__bf16*)(ws + WT_OFF);
    __bf16* op0 = (__bf16*)(ws + HN_OFF);   // hn dead during flash
    __bf16* op1 = (__bf16*)(ws + O1_OFF);
    __bf16* attn = qb;                      // q dead after flash
    float* out = (float*)d_out;

    bool use4 = (ws_size >= NEED4);
    __bf16* op2 = use4 ? (__bf16*)(ws + O2_OFF) : op0;
    __bf16* op3 = use4 ? (__bf16*)(ws + O3_OFF) : op1;
    float*  lp  = use4 ? (float*)(ws + ML4_OFF) : (float*)(ws + ML_OFF);
    float*  gs  = use4 ? (float*)(ws + GS4_OFF) : (float*)(ws + GS_OFF);

    zero_stats<<<1, 256, 0, stream>>>(gs);
    wt_kernel<<<dim3(16, 16, 4), 256, 0, stream>>>(wq, wk, wv, wo, wt);
    gn_stats<<<dim3(128, 4), 256, 0, stream>>>(x, gs);
    gn_apply<<<dim3(128, 4), 256, 0, stream>>>(x, gs, gsc, gbi, hn);
    proj_qkv<<<dim3(128, 4, 3), 256, 0, stream>>>(hn, wt, bq, bk, bv, qb, kb, v4);
    if (use4) {
        flash_kernel<4><<<1024, 256, 0, stream>>>(qb, kb, v4, op0, op1, op2, op3, lp);
        combine_kernel<4><<<256, 256, 0, stream>>>(op0, op1, op2, op3, lp, attn);
    } else {
        flash_kernel<2><<<512, 256, 0, stream>>>(qb, kb, v4, op0, op1, op2, op3, lp);
        combine_kernel<2><<<256, 256, 0, stream>>>(op0, op1, op2, op3, lp, attn);
    }
    proj_out<<<dim3(128, 4), 256, 0, stream>>>(attn, wt + (size_t)3 * C_DIM * C_DIM, bo, x, out);
}

// Round 7
// 459.783 us; speedup vs baseline: 2.8528x; 2.8528x over previous
//
#include <hip/hip_runtime.h>

// ---------------------------------------------------------------------------
// AttnBlock: GroupNorm -> q,k,v 1x1 conv -> softmax(QK^T/sqrt(C)) V -> out proj
// B=4, H=W=64 (4096 positions/batch), C=512, 32 groups.
// bf16 MFMA pipeline, fp32 accumulation. Split-K flash (2-way), no-max
// softmax, XCD-aware remap (R2: FETCH 90->41.5MB, verified), V in registers
// (R4: LDS 69->37.9KB).
// R6/R7 (resubmit after infra failure): K DOUBLE-BUFFER. R4's regression
// isolated the dominant stall: K(kt+1) staging was issued right before the
// (short) PV phase and drained at barrier C -> exposed L2 latency every iter.
// Now K(kt+1) is issued at the TOP of the iteration into the alternate 32KB
// buffer, covered by the full S-phase + softmax (~2000 cyc), drained by the
// existing barrier A. Barrier C has ZERO VMEM in flight (PV uses only regs +
// P-LDS). LDS = 2x32K + 5K = 70656 B -> still 2 blocks/CU. Buffer swap is
// race-free with the existing 2 barriers (reads of buf[t] end before barrier
// A of iter t; buf[t] is rewritten at iter t+1 top, after barrier C).
// ---------------------------------------------------------------------------

typedef __attribute__((ext_vector_type(8))) __bf16 bf16x8;
typedef __attribute__((ext_vector_type(4))) __bf16 bf16x4;
typedef __attribute__((ext_vector_type(4))) float  floatx4;

#define C_DIM 512
#define SPB   4096
#define MTOT  16384

// workspace layout (bytes), peak ~84.4 MiB
#define HN_OFF  ((size_t)0)            // hn bf16 [16384][512]; reused as Opart0
#define Q_OFF   ((size_t)16 << 20)     // q bf16 (pre-scaled); reused as attn
#define K_OFF   ((size_t)32 << 20)     // k bf16
#define V4_OFF  ((size_t)48 << 20)     // v bf16 grouped [B][512 pg][512 ch][8key]
#define WT_OFF  ((size_t)64 << 20)     // wT bf16 [4][512 out][512 in]
#define O1_OFF  ((size_t)68 << 20)     // Opart1 bf16 [16384][512]
#define ML_OFF  ((size_t)84 << 20)     // lpart fp32 [2][16384]
#define GS_OFF  (ML_OFF + (size_t)(256 << 10))  // gstats fp32 [128][2]

__device__ inline floatx4 mfma16(bf16x8 a, bf16x8 b, floatx4 c) {
    return __builtin_amdgcn_mfma_f32_16x16x32_bf16(a, b, c, 0, 0, 0);
}

__device__ inline void gload16(const void* g, void* lds) {
    __builtin_amdgcn_global_load_lds(
        (const __attribute__((address_space(1))) unsigned int*)g,
        (__attribute__((address_space(3))) unsigned int*)lds, 16, 0, 0);
}

// ---------------------------------------------------------------------------
// GroupNorm stats: grid (128, 4) - block = (batch,group) x spatial quarter.
// ---------------------------------------------------------------------------
__global__ __launch_bounds__(256) void zero_stats(float* gstats) {
    gstats[threadIdx.x] = 0.f;
}

__global__ __launch_bounds__(256) void gn_stats(
    const float* __restrict__ x, float* __restrict__ gstats) {
    int bg = blockIdx.x;                    // b*32+g
    int b = bg >> 5, g = bg & 31;
    int tid = threadIdx.x;
    int cq = tid & 3, s0 = tid >> 2;
    const float* base = x + (size_t)b * SPB * C_DIM + g * 16 + cq * 4
                          + (size_t)blockIdx.y * 1024 * C_DIM;
    float sum = 0.f, sq = 0.f;
#pragma unroll 4
    for (int i = 0; i < 16; ++i) {
        floatx4 v = *(const floatx4*)(base + (size_t)(i * 64 + s0) * C_DIM);
        sum += v[0] + v[1] + v[2] + v[3];
        sq  += v[0]*v[0] + v[1]*v[1] + v[2]*v[2] + v[3]*v[3];
    }
#pragma unroll
    for (int off = 1; off < 64; off <<= 1) {
        sum += __shfl_xor(sum, off);
        sq  += __shfl_xor(sq,  off);
    }
    __shared__ float sm[8];
    int w = tid >> 6, lane = tid & 63;
    if (lane == 0) { sm[w] = sum; sm[4 + w] = sq; }
    __syncthreads();
    if (tid == 0) {
        atomicAdd(&gstats[bg * 2],     sm[0] + sm[1] + sm[2] + sm[3]);
        atomicAdd(&gstats[bg * 2 + 1], sm[4] + sm[5] + sm[6] + sm[7]);
    }
}

__global__ __launch_bounds__(256) void gn_apply(
    const float* __restrict__ x, const float* __restrict__ gstats,
    const float* __restrict__ gsc, const float* __restrict__ gbi,
    __bf16* __restrict__ hn) {
    int bg = blockIdx.x;
    int b = bg >> 5, g = bg & 31;
    int tid = threadIdx.x;
    int cq = tid & 3, s0 = tid >> 2;
    float S  = gstats[bg * 2], Qs = gstats[bg * 2 + 1];
    float mean = S * (1.f / 65536.f);
    float var  = Qs * (1.f / 65536.f) - mean * mean;
    float rstd = rsqrtf(var + 1e-6f);
    float sc[4], bi[4];
#pragma unroll
    for (int j = 0; j < 4; ++j) {
        float s_ = gsc[g * 16 + cq * 4 + j] * rstd;
        sc[j] = s_;
        bi[j] = gbi[g * 16 + cq * 4 + j] - mean * s_;
    }
    size_t off = (size_t)b * SPB * C_DIM + g * 16 + cq * 4
               + (size_t)blockIdx.y * 1024 * C_DIM;
    const float* base = x + off;
    __bf16* hbase = hn + off;
#pragma unroll 4
    for (int i = 0; i < 16; ++i) {
        floatx4 v = *(const floatx4*)(base + (size_t)(i * 64 + s0) * C_DIM);
        bf16x4 o;
#pragma unroll
        for (int j = 0; j < 4; ++j) o[j] = (__bf16)(v[j] * sc[j] + bi[j]);
        *(bf16x4*)(hbase + (size_t)(i * 64 + s0) * C_DIM) = o;
    }
}

// ---------------------------------------------------------------------------
// Weight transpose + bf16 convert: wT[z][n][k] = w_z[k][n]
// ---------------------------------------------------------------------------
__global__ __launch_bounds__(256) void wt_kernel(
    const float* __restrict__ w0, const float* __restrict__ w1,
    const float* __restrict__ w2, const float* __restrict__ w3,
    __bf16* __restrict__ wt) {
    const float* srcs[4] = {w0, w1, w2, w3};
    const float* src = srcs[blockIdx.z];
    __bf16* dst = wt + (size_t)blockIdx.z * C_DIM * C_DIM;
    __shared__ float tile[32][33];
    int tx = threadIdx.x & 31, ty = threadIdx.x >> 5;
    int gx = blockIdx.x * 32, gy = blockIdx.y * 32;
#pragma unroll
    for (int i = 0; i < 4; ++i)
        tile[ty + i * 8][tx] = src[(size_t)(gy + ty + i * 8) * C_DIM + gx + tx];
    __syncthreads();
#pragma unroll
    for (int i = 0; i < 4; ++i) {
        int n = gx + ty + i * 8;
        int k = gy + tx;
        dst[(size_t)n * C_DIM + k] = (__bf16)tile[tx][ty + i * 8];
    }
}

// ---------------------------------------------------------------------------
// q/k/v projection GEMM: 128x128 tile, BK=32, async LDS staging.
// ---------------------------------------------------------------------------
__global__ __launch_bounds__(256, 2) void proj_qkv(
    const __bf16* __restrict__ hn, const __bf16* __restrict__ wt_all,
    const float* __restrict__ bq, const float* __restrict__ bk,
    const float* __restrict__ bv, __bf16* __restrict__ qout,
    __bf16* __restrict__ kout, __bf16* __restrict__ v4out) {
    int z = blockIdx.z;
    const __bf16* wt = wt_all + (size_t)z * C_DIM * C_DIM;
    const float* bias = (z == 0) ? bq : (z == 1) ? bk : bv;
    __shared__ __bf16 Alds[128 * 32];
    __shared__ __bf16 Blds[128 * 32];
    int tid = threadIdx.x, lane = tid & 63, w = tid >> 6;
    int c = lane & 15, quad = lane >> 4;
    int wm = w & 1, wn = w >> 1;
    int mbase = blockIdx.x * 128, nbase = blockIdx.y * 128;
    floatx4 acc[4][4] = {};
    for (int kb = 0; kb < 16; ++kb) {
        __syncthreads();
#pragma unroll
        for (int p = 0; p < 2; ++p) {
            int chunk0 = w * 128 + p * 64;
            int chunk = chunk0 + lane;
            int row = chunk >> 2, qk = chunk & 3;
            gload16(hn + (size_t)(mbase + row) * C_DIM + kb * 32 + qk * 8, Alds + chunk0 * 8);
            gload16(wt + (size_t)(nbase + row) * C_DIM + kb * 32 + qk * 8, Blds + chunk0 * 8);
        }
        __syncthreads();
        bf16x8 af[4], bfr[4];
#pragma unroll
        for (int mt = 0; mt < 4; ++mt)
            af[mt] = *(const bf16x8*)(Alds + (wm * 64 + mt * 16 + c) * 32 + quad * 8);
#pragma unroll
        for (int nt = 0; nt < 4; ++nt)
            bfr[nt] = *(const bf16x8*)(Blds + (wn * 64 + nt * 16 + c) * 32 + quad * 8);
#pragma unroll
        for (int mt = 0; mt < 4; ++mt)
#pragma unroll
            for (int nt = 0; nt < 4; ++nt)
                acc[mt][nt] = mfma16(af[mt], bfr[nt], acc[mt][nt]);
    }
    float scale = (z == 0) ? 0.0441941738241592f : 1.0f;   // 512^-0.5
#pragma unroll
    for (int nt = 0; nt < 4; ++nt) {
        int n = nbase + wn * 64 + nt * 16 + c;
        float bval = bias[n];
#pragma unroll
        for (int mt = 0; mt < 4; ++mt) {
            int m0 = mbase + wm * 64 + mt * 16 + quad * 4;
#pragma unroll
            for (int r = 0; r < 4; ++r) {
                int m = m0 + r;
                float val = (acc[mt][nt][r] + bval) * scale;
                if (z == 0)      qout[(size_t)m * C_DIM + n] = (__bf16)val;
                else if (z == 1) kout[(size_t)m * C_DIM + n] = (__bf16)val;
                else {
                    int bb = m >> 12, pos = m & 4095;
                    v4out[((size_t)(bb * 512 + (pos >> 3)) * C_DIM + n) * 8 + (pos & 7)] = (__bf16)val;
                }
            }
        }
    }
}

// ---------------------------------------------------------------------------
// Split-K flash attention, K double-buffered. Grid 512 = qt(64) x [b(4)xh(2)].
// XCD-aware remap: bid%8 == XCD (R2-verified L2 fit: 2MB K + 2MB V per XCD).
// Per iter: [issue K(kt+1)->buf^1, V(kt)->regs] S-phase(buf) | softmax |
// P-write | barrier A (drains K+V, both covered by S-phase) | PV (regs+P-LDS)
// | barrier C (no VMEM in flight). No-max softmax; O partials bf16 + l fp32.
// ---------------------------------------------------------------------------
__device__ inline void stage_K(const __bf16* kbase, int key0,
                               __bf16* Klds, int w, int lane) {
#pragma unroll
    for (int p = 0; p < 8; ++p) {
        int chunk0 = w * 512 + p * 64;
        int chunk = chunk0 + lane;
        gload16(kbase + (size_t)(key0 + (chunk & 31)) * C_DIM + (chunk >> 5) * 8,
                Klds + chunk0 * 8);
    }
}

__global__ __launch_bounds__(256, 2) void flash_kernel(
    const __bf16* __restrict__ q, const __bf16* __restrict__ kmat,
    const __bf16* __restrict__ v4, __bf16* __restrict__ op0,
    __bf16* __restrict__ op1, float* __restrict__ lpart) {
    __shared__ __bf16 Klds[2][16384];  // 2 x 32 KB: [cg 64][key 32][8ch]
    __shared__ __bf16 Plds[64 * 40];   // 5 KB : [row 64][key 32 + pad 8]
    int tid = threadIdx.x, lane = tid & 63, w = tid >> 6;
    int c = lane & 15, quad = lane >> 4;
    int bid = blockIdx.x;
    // XCD-aware decode: bid%8 selects (b,h); bid/8 selects q-tile.
    int xcd = bid & 7;
    int b = xcd >> 1, h = xcd & 1, qt = bid >> 3;

    const __bf16* qp = q + ((size_t)(b * SPB + qt * 64 + w * 16 + c)) * C_DIM + quad * 8;
    bf16x8 qf[16];
#pragma unroll
    for (int ks = 0; ks < 16; ++ks) qf[ks] = *(const bf16x8*)(qp + ks * 32);
    floatx4 o[4][8];
#pragma unroll
    for (int mg = 0; mg < 4; ++mg)
#pragma unroll
        for (int t = 0; t < 8; ++t) o[mg][t] = (floatx4){0.f, 0.f, 0.f, 0.f};
    float l_r[4] = {0.f, 0.f, 0.f, 0.f};

    const __bf16* kbase = kmat + (size_t)b * SPB * C_DIM;
    const __bf16* vbase = v4 + (size_t)b * 512 * C_DIM * 8;

    stage_K(kbase, h * 2048, &Klds[0][0], w, lane);   // prologue: K(0) -> buf0
    __syncthreads();                                  // drain: K(0) ready

    int cur = 0;
    for (int kt = 0; kt < 64; ++kt) {
        int key0 = h * 2048 + kt * 32;
        // issue K(kt+1) -> other buffer; covered by S-phase, drained at A
        if (kt < 63)
            stage_K(kbase, key0 + 32, &Klds[cur ^ 1][0], w, lane);
        // issue V(kt) -> registers; consumed in PV after barrier A
        const __bf16* vp = vbase
            + ((size_t)((key0 >> 3) + quad) * C_DIM + w * 128 + c) * 8;
        bf16x8 vreg[8];
#pragma unroll
        for (int t = 0; t < 8; ++t)
            vreg[t] = *(const bf16x8*)(vp + (size_t)t * 16 * 8);
        // ---- S = Q K^T: 16 q-rows x 32 keys per wave (K(kt) in buf cur) ----
        const __bf16* Kb = &Klds[cur][0];
        floatx4 s0 = (floatx4){0.f,0.f,0.f,0.f}, s1 = (floatx4){0.f,0.f,0.f,0.f};
#pragma unroll
        for (int ks = 0; ks < 16; ++ks) {
            bf16x8 k0 = *(const bf16x8*)(Kb + (((ks * 4 + quad) * 32) + c) * 8);
            bf16x8 k1 = *(const bf16x8*)(Kb + (((ks * 4 + quad) * 32) + c + 16) * 8);
            s0 = mfma16(qf[ks], k0, s0);
            s1 = mfma16(qf[ks], k1, s1);
        }
        // ---- no-max softmax: p = exp(s), accumulate l per-lane ----
#pragma unroll
        for (int r = 0; r < 4; ++r) {
            float p0 = __expf(s0[r]);
            float p1 = __expf(s1[r]);
            l_r[r] += p0 + p1;
            int row = w * 16 + quad * 4 + r;
            Plds[row * 40 + c]      = (__bf16)p0;
            Plds[row * 40 + c + 16] = (__bf16)p1;
        }
        __syncthreads();   // A: P visible; K(kt+1) + V(kt) drained (covered)
        // ---- O += P V (channel-split: all 64 rows, chans w*128..) ----
        bf16x8 pf[4];
#pragma unroll
        for (int mg = 0; mg < 4; ++mg)
            pf[mg] = *(const bf16x8*)(Plds + (mg * 16 + c) * 40 + quad * 8);
#pragma unroll
        for (int t = 0; t < 8; ++t) {
#pragma unroll
            for (int mg = 0; mg < 4; ++mg)
                o[mg][t] = mfma16(pf[mg], vreg[t], o[mg][t]);
        }
        __syncthreads();   // C: P reads done; NO VMEM in flight (cheap)
        cur ^= 1;
    }
    // ---- epilogue: reduce l across the 16 lanes sharing each row ----
#pragma unroll
    for (int r = 0; r < 4; ++r) {
        float l = l_r[r];
        l += __shfl_xor(l, 1);
        l += __shfl_xor(l, 2);
        l += __shfl_xor(l, 4);
        l += __shfl_xor(l, 8);
        l_r[r] = l;
    }
    if (c == 0) {
#pragma unroll
        for (int r = 0; r < 4; ++r) {
            int grow = b * SPB + qt * 64 + w * 16 + quad * 4 + r;
            lpart[h * MTOT + grow] = l_r[r];
        }
    }
    __bf16* ob = h ? op1 : op0;
#pragma unroll
    for (int mg = 0; mg < 4; ++mg)
#pragma unroll
        for (int t = 0; t < 8; ++t)
#pragma unroll
            for (int r = 0; r < 4; ++r) {
                int grow = b * SPB + qt * 64 + mg * 16 + quad * 4 + r;
                ob[(size_t)grow * C_DIM + w * 128 + t * 16 + c] = (__bf16)o[mg][t][r];
            }
}

// ---------------------------------------------------------------------------
// Combine key-half partials: attn = (O0 + O1) / (l0 + l1)
// ---------------------------------------------------------------------------
__global__ __launch_bounds__(256) void combine_kernel(
    const __bf16* __restrict__ o0, const __bf16* __restrict__ o1,
    const float* __restrict__ lpart, __bf16* __restrict__ attn) {
    int tid = threadIdx.x, lane = tid & 63, w = tid >> 6;
    int rbase = blockIdx.x * 64 + w * 16;
    for (int rr = 0; rr < 16; ++rr) {
        int row = rbase + rr;
        float inv = 1.f / (lpart[row] + lpart[MTOT + row]);
        bf16x8 v0 = *(const bf16x8*)(o0 + (size_t)row * C_DIM + lane * 8);
        bf16x8 v1 = *(const bf16x8*)(o1 + (size_t)row * C_DIM + lane * 8);
        bf16x8 r;
#pragma unroll
        for (int j = 0; j < 8; ++j) r[j] = (__bf16)(((float)v0[j] + (float)v1[j]) * inv);
        *(bf16x8*)(attn + (size_t)row * C_DIM + lane * 8) = r;
    }
}

// ---------------------------------------------------------------------------
// out = x + attn @ wo + bo (fp32 output)
// ---------------------------------------------------------------------------
__global__ __launch_bounds__(256, 2) void proj_out(
    const __bf16* __restrict__ attn, const __bf16* __restrict__ wot,
    const float* __restrict__ bo, const float* __restrict__ x,
    float* __restrict__ out) {
    __shared__ __bf16 Alds[128 * 32];
    __shared__ __bf16 Blds[128 * 32];
    int tid = threadIdx.x, lane = tid & 63, w = tid >> 6;
    int c = lane & 15, quad = lane >> 4;
    int wm = w & 1, wn = w >> 1;
    int mbase = blockIdx.x * 128, nbase = blockIdx.y * 128;
    floatx4 acc[4][4] = {};
    for (int kb = 0; kb < 16; ++kb) {
        __syncthreads();
#pragma unroll
        for (int p = 0; p < 2; ++p) {
            int chunk0 = w * 128 + p * 64;
            int chunk = chunk0 + lane;
            int row = chunk >> 2, qk = chunk & 3;
            gload16(attn + (size_t)(mbase + row) * C_DIM + kb * 32 + qk * 8, Alds + chunk0 * 8);
            gload16(wot + (size_t)(nbase + row) * C_DIM + kb * 32 + qk * 8, Blds + chunk0 * 8);
        }
        __syncthreads();
        bf16x8 af[4], bfr[4];
#pragma unroll
        for (int mt = 0; mt < 4; ++mt)
            af[mt] = *(const bf16x8*)(Alds + (wm * 64 + mt * 16 + c) * 32 + quad * 8);
#pragma unroll
        for (int nt = 0; nt < 4; ++nt)
            bfr[nt] = *(const bf16x8*)(Blds + (wn * 64 + nt * 16 + c) * 32 + quad * 8);
#pragma unroll
        for (int mt = 0; mt < 4; ++mt)
#pragma unroll
            for (int nt = 0; nt < 4; ++nt)
                acc[mt][nt] = mfma16(af[mt], bfr[nt], acc[mt][nt]);
    }
#pragma unroll
    for (int nt = 0; nt < 4; ++nt) {
        int n = nbase + wn * 64 + nt * 16 + c;
        float bval = bo[n];
#pragma unroll
        for (int mt = 0; mt < 4; ++mt) {
            int m0 = mbase + wm * 64 + mt * 16 + quad * 4;
#pragma unroll
            for (int r = 0; r < 4; ++r) {
                size_t idx = (size_t)(m0 + r) * C_DIM + n;
                out[idx] = acc[mt][nt][r] + bval + x[idx];
            }
        }
    }
}

// ---------------------------------------------------------------------------
extern "C" void kernel_launch(void* const* d_in, const int* in_sizes, int n_in,
                              void* d_out, int out_size, void* d_ws, size_t ws_size,
                              hipStream_t stream) {
    const float* x   = (const float*)d_in[0];
    const float* gsc = (const float*)d_in[1];
    const float* gbi = (const float*)d_in[2];
    const float* wq  = (const float*)d_in[3];
    const float* bq  = (const float*)d_in[4];
    const float* wk  = (const float*)d_in[5];
    const float* bk  = (const float*)d_in[6];
    const float* wv  = (const float*)d_in[7];
    const float* bv  = (const float*)d_in[8];
    const float* wo  = (const float*)d_in[9];
    const float* bo  = (const float*)d_in[10];
    char* ws = (char*)d_ws;
    __bf16* hn  = (__bf16*)(ws + HN_OFF);
    __bf16* qb  = (__bf16*)(ws + Q_OFF);
    __bf16* kb  = (__bf16*)(ws + K_OFF);
    __bf16* v4  = (__bf16*)(ws + V4_OFF);
    __bf16* wt  = (__bf16*)(ws + WT_OFF);
    __bf16* op0 = (__bf16*)(ws + HN_OFF);   // hn dead during flash
    __bf16* op1 = (__bf16*)(ws + O1_OFF);
    float*  lp  = (float*)(ws + ML_OFF);
    float*  gs  = (float*)(ws + GS_OFF);
    __bf16* attn = qb;                      // q dead after flash
    float* out = (float*)d_out;

    zero_stats<<<1, 256, 0, stream>>>(gs);
    wt_kernel<<<dim3(16, 16, 4), 256, 0, stream>>>(wq, wk, wv, wo, wt);
    gn_stats<<<dim3(128, 4), 256, 0, stream>>>(x, gs);
    gn_apply<<<dim3(128, 4), 256, 0, stream>>>(x, gs, gsc, gbi, hn);
    proj_qkv<<<dim3(128, 4, 3), 256, 0, stream>>>(hn, wt, bq, bk, bv, qb, kb, v4);
    flash_kernel<<<512, 256, 0, stream>>>(qb, kb, v4, op0, op1, lp);
    combine_kernel<<<256, 256, 0, stream>>>(op0, op1, lp, attn);
    proj_out<<<dim3(128, 4), 256, 0, stream>>>(attn, wt + (size_t)3 * C_DIM * C_DIM, bo, x, out);
}

// Round 8
// 434.127 us; speedup vs baseline: 3.0214x; 1.0591x over previous
//
#include <hip/hip_runtime.h>

// ---------------------------------------------------------------------------
// AttnBlock: GroupNorm -> q,k,v 1x1 conv -> softmax(QK^T/sqrt(C)) V -> out proj
// B=4, H=W=64 (4096 positions/batch), C=512, 32 groups.
// bf16 MFMA pipeline, fp32 accumulation. Split-K flash (2-way), no-max
// softmax, XCD-aware block remap (R2: FETCH 90->41.5 MB, verified).
// R8: revert flash to the R2 champion structure (V staged to LDS via DMA,
// K staged post-A with PV cover — ledger: R2=244 < R7 K-dbuf+V-reg=273 ≈
// R4 V-reg=274) + T5 s_setprio(1) around both MFMA clusters. T5 prior:
// +4-7% on attn with co-resident blocks at independent phases (m191) —
// exactly this config (2 independent blocks/CU). Clean A/B vs 244.
// ---------------------------------------------------------------------------

typedef __attribute__((ext_vector_type(8))) __bf16 bf16x8;
typedef __attribute__((ext_vector_type(4))) __bf16 bf16x4;
typedef __attribute__((ext_vector_type(4))) float  floatx4;

#define C_DIM 512
#define SPB   4096
#define MTOT  16384

// workspace layout (bytes), peak ~84.4 MiB
#define HN_OFF  ((size_t)0)            // hn bf16 [16384][512]; reused as Opart0
#define Q_OFF   ((size_t)16 << 20)     // q bf16 (pre-scaled); reused as attn
#define K_OFF   ((size_t)32 << 20)     // k bf16
#define V4_OFF  ((size_t)48 << 20)     // v bf16 grouped [B][512 pg][512 ch][8key]
#define WT_OFF  ((size_t)64 << 20)     // wT bf16 [4][512 out][512 in]
#define O1_OFF  ((size_t)68 << 20)     // Opart1 bf16 [16384][512]
#define ML_OFF  ((size_t)84 << 20)     // lpart fp32 [2][16384]
#define GS_OFF  (ML_OFF + (size_t)(256 << 10))  // gstats fp32 [128][2]

__device__ inline floatx4 mfma16(bf16x8 a, bf16x8 b, floatx4 c) {
    return __builtin_amdgcn_mfma_f32_16x16x32_bf16(a, b, c, 0, 0, 0);
}

__device__ inline void gload16(const void* g, void* lds) {
    __builtin_amdgcn_global_load_lds(
        (const __attribute__((address_space(1))) unsigned int*)g,
        (__attribute__((address_space(3))) unsigned int*)lds, 16, 0, 0);
}

// ---------------------------------------------------------------------------
// GroupNorm stats: grid (128, 4) - block = (batch,group) x spatial quarter.
// ---------------------------------------------------------------------------
__global__ __launch_bounds__(256) void zero_stats(float* gstats) {
    gstats[threadIdx.x] = 0.f;
}

__global__ __launch_bounds__(256) void gn_stats(
    const float* __restrict__ x, float* __restrict__ gstats) {
    int bg = blockIdx.x;                    // b*32+g
    int b = bg >> 5, g = bg & 31;
    int tid = threadIdx.x;
    int cq = tid & 3, s0 = tid >> 2;
    const float* base = x + (size_t)b * SPB * C_DIM + g * 16 + cq * 4
                          + (size_t)blockIdx.y * 1024 * C_DIM;
    float sum = 0.f, sq = 0.f;
#pragma unroll 4
    for (int i = 0; i < 16; ++i) {
        floatx4 v = *(const floatx4*)(base + (size_t)(i * 64 + s0) * C_DIM);
        sum += v[0] + v[1] + v[2] + v[3];
        sq  += v[0]*v[0] + v[1]*v[1] + v[2]*v[2] + v[3]*v[3];
    }
#pragma unroll
    for (int off = 1; off < 64; off <<= 1) {
        sum += __shfl_xor(sum, off);
        sq  += __shfl_xor(sq,  off);
    }
    __shared__ float sm[8];
    int w = tid >> 6, lane = tid & 63;
    if (lane == 0) { sm[w] = sum; sm[4 + w] = sq; }
    __syncthreads();
    if (tid == 0) {
        atomicAdd(&gstats[bg * 2],     sm[0] + sm[1] + sm[2] + sm[3]);
        atomicAdd(&gstats[bg * 2 + 1], sm[4] + sm[5] + sm[6] + sm[7]);
    }
}

__global__ __launch_bounds__(256) void gn_apply(
    const float* __restrict__ x, const float* __restrict__ gstats,
    const float* __restrict__ gsc, const float* __restrict__ gbi,
    __bf16* __restrict__ hn) {
    int bg = blockIdx.x;
    int b = bg >> 5, g = bg & 31;
    int tid = threadIdx.x;
    int cq = tid & 3, s0 = tid >> 2;
    float S  = gstats[bg * 2], Qs = gstats[bg * 2 + 1];
    float mean = S * (1.f / 65536.f);
    float var  = Qs * (1.f / 65536.f) - mean * mean;
    float rstd = rsqrtf(var + 1e-6f);
    float sc[4], bi[4];
#pragma unroll
    for (int j = 0; j < 4; ++j) {
        float s_ = gsc[g * 16 + cq * 4 + j] * rstd;
        sc[j] = s_;
        bi[j] = gbi[g * 16 + cq * 4 + j] - mean * s_;
    }
    size_t off = (size_t)b * SPB * C_DIM + g * 16 + cq * 4
               + (size_t)blockIdx.y * 1024 * C_DIM;
    const float* base = x + off;
    __bf16* hbase = hn + off;
#pragma unroll 4
    for (int i = 0; i < 16; ++i) {
        floatx4 v = *(const floatx4*)(base + (size_t)(i * 64 + s0) * C_DIM);
        bf16x4 o;
#pragma unroll
        for (int j = 0; j < 4; ++j) o[j] = (__bf16)(v[j] * sc[j] + bi[j]);
        *(bf16x4*)(hbase + (size_t)(i * 64 + s0) * C_DIM) = o;
    }
}

// ---------------------------------------------------------------------------
// Weight transpose + bf16 convert: wT[z][n][k] = w_z[k][n]
// ---------------------------------------------------------------------------
__global__ __launch_bounds__(256) void wt_kernel(
    const float* __restrict__ w0, const float* __restrict__ w1,
    const float* __restrict__ w2, const float* __restrict__ w3,
    __bf16* __restrict__ wt) {
    const float* srcs[4] = {w0, w1, w2, w3};
    const float* src = srcs[blockIdx.z];
    __bf16* dst = wt + (size_t)blockIdx.z * C_DIM * C_DIM;
    __shared__ float tile[32][33];
    int tx = threadIdx.x & 31, ty = threadIdx.x >> 5;
    int gx = blockIdx.x * 32, gy = blockIdx.y * 32;
#pragma unroll
    for (int i = 0; i < 4; ++i)
        tile[ty + i * 8][tx] = src[(size_t)(gy + ty + i * 8) * C_DIM + gx + tx];
    __syncthreads();
#pragma unroll
    for (int i = 0; i < 4; ++i) {
        int n = gx + ty + i * 8;
        int k = gy + tx;
        dst[(size_t)n * C_DIM + k] = (__bf16)tile[tx][ty + i * 8];
    }
}

// ---------------------------------------------------------------------------
// q/k/v projection GEMM: 128x128 tile, BK=32, async LDS staging.
// ---------------------------------------------------------------------------
__global__ __launch_bounds__(256, 2) void proj_qkv(
    const __bf16* __restrict__ hn, const __bf16* __restrict__ wt_all,
    const float* __restrict__ bq, const float* __restrict__ bk,
    const float* __restrict__ bv, __bf16* __restrict__ qout,
    __bf16* __restrict__ kout, __bf16* __restrict__ v4out) {
    int z = blockIdx.z;
    const __bf16* wt = wt_all + (size_t)z * C_DIM * C_DIM;
    const float* bias = (z == 0) ? bq : (z == 1) ? bk : bv;
    __shared__ __bf16 Alds[128 * 32];
    __shared__ __bf16 Blds[128 * 32];
    int tid = threadIdx.x, lane = tid & 63, w = tid >> 6;
    int c = lane & 15, quad = lane >> 4;
    int wm = w & 1, wn = w >> 1;
    int mbase = blockIdx.x * 128, nbase = blockIdx.y * 128;
    floatx4 acc[4][4] = {};
    for (int kb = 0; kb < 16; ++kb) {
        __syncthreads();
#pragma unroll
        for (int p = 0; p < 2; ++p) {
            int chunk0 = w * 128 + p * 64;
            int chunk = chunk0 + lane;
            int row = chunk >> 2, qk = chunk & 3;
            gload16(hn + (size_t)(mbase + row) * C_DIM + kb * 32 + qk * 8, Alds + chunk0 * 8);
            gload16(wt + (size_t)(nbase + row) * C_DIM + kb * 32 + qk * 8, Blds + chunk0 * 8);
        }
        __syncthreads();
        bf16x8 af[4], bfr[4];
#pragma unroll
        for (int mt = 0; mt < 4; ++mt)
            af[mt] = *(const bf16x8*)(Alds + (wm * 64 + mt * 16 + c) * 32 + quad * 8);
#pragma unroll
        for (int nt = 0; nt < 4; ++nt)
            bfr[nt] = *(const bf16x8*)(Blds + (wn * 64 + nt * 16 + c) * 32 + quad * 8);
#pragma unroll
        for (int mt = 0; mt < 4; ++mt)
#pragma unroll
            for (int nt = 0; nt < 4; ++nt)
                acc[mt][nt] = mfma16(af[mt], bfr[nt], acc[mt][nt]);
    }
    float scale = (z == 0) ? 0.0441941738241592f : 1.0f;   // 512^-0.5
#pragma unroll
    for (int nt = 0; nt < 4; ++nt) {
        int n = nbase + wn * 64 + nt * 16 + c;
        float bval = bias[n];
#pragma unroll
        for (int mt = 0; mt < 4; ++mt) {
            int m0 = mbase + wm * 64 + mt * 16 + quad * 4;
#pragma unroll
            for (int r = 0; r < 4; ++r) {
                int m = m0 + r;
                float val = (acc[mt][nt][r] + bval) * scale;
                if (z == 0)      qout[(size_t)m * C_DIM + n] = (__bf16)val;
                else if (z == 1) kout[(size_t)m * C_DIM + n] = (__bf16)val;
                else {
                    int bb = m >> 12, pos = m & 4095;
                    v4out[((size_t)(bb * 512 + (pos >> 3)) * C_DIM + n) * 8 + (pos & 7)] = (__bf16)val;
                }
            }
        }
    }
}

// ---------------------------------------------------------------------------
// Split-K flash attention, pipelined (R2 champion structure).
// Grid 512 = qt(64) x [b(4) x h(2)], bid%8 == XCD (L2-fit, R2-verified).
// Per iter: [issue V(kt)->LDS] S-phase | softmax | P-write | barrier A
// (V drained, covered by S) | [issue K(kt+1)->LDS] PV | barrier C (K drained,
// covered by PV). T5 setprio(1) around both MFMA clusters.
// ---------------------------------------------------------------------------
__device__ inline void stage_K(const __bf16* kbase, int key0,
                               __bf16* Klds, int w, int lane) {
#pragma unroll
    for (int p = 0; p < 8; ++p) {
        int chunk0 = w * 512 + p * 64;
        int chunk = chunk0 + lane;
        gload16(kbase + (size_t)(key0 + (chunk & 31)) * C_DIM + (chunk >> 5) * 8,
                Klds + chunk0 * 8);
    }
}

__device__ inline void stage_V(const __bf16* vsrc, __bf16* Vlds, int w, int lane) {
#pragma unroll
    for (int p = 0; p < 8; ++p) {
        int chunk0 = w * 512 + p * 64;
        gload16(vsrc + (size_t)(chunk0 + lane) * 8, Vlds + chunk0 * 8);
    }
}

__global__ __launch_bounds__(256, 2) void flash_kernel(
    const __bf16* __restrict__ q, const __bf16* __restrict__ kmat,
    const __bf16* __restrict__ v4, __bf16* __restrict__ op0,
    __bf16* __restrict__ op1, float* __restrict__ lpart) {
    __shared__ __bf16 Klds[16384];     // 32 KB: [cg 64][key 32][8ch]
    __shared__ __bf16 Vlds[16384];     // 32 KB: [kg 4][ch 512][8key]
    __shared__ __bf16 Plds[64 * 40];   // 5 KB: [row 64][key 32 + pad 8]
    int tid = threadIdx.x, lane = tid & 63, w = tid >> 6;
    int c = lane & 15, quad = lane >> 4;
    int bid = blockIdx.x;
    // XCD-aware decode: bid%8 selects (b,h); bid/8 selects q-tile.
    int xcd = bid & 7;
    int b = xcd >> 1, h = xcd & 1, qt = bid >> 3;

    const __bf16* qp = q + ((size_t)(b * SPB + qt * 64 + w * 16 + c)) * C_DIM + quad * 8;
    bf16x8 qf[16];
#pragma unroll
    for (int ks = 0; ks < 16; ++ks) qf[ks] = *(const bf16x8*)(qp + ks * 32);
    floatx4 o[4][8];
#pragma unroll
    for (int mg = 0; mg < 4; ++mg)
#pragma unroll
        for (int t = 0; t < 8; ++t) o[mg][t] = (floatx4){0.f, 0.f, 0.f, 0.f};
    float l_r[4] = {0.f, 0.f, 0.f, 0.f};

    const __bf16* kbase = kmat + (size_t)b * SPB * C_DIM;
    const __bf16* vbase = v4 + (size_t)b * 512 * C_DIM * 8;

    stage_K(kbase, h * 2048, Klds, w, lane);   // prologue: K(0)
    __syncthreads();                           // drain: K(0) ready

    for (int kt = 0; kt < 64; ++kt) {
        int key0 = h * 2048 + kt * 32;
        // issue V(kt): latency covered by S-phase + softmax
        stage_V(vbase + (size_t)(key0 >> 3) * C_DIM * 8, Vlds, w, lane);
        // ---- S = Q K^T: 16 q-rows x 32 keys per wave (K(kt) in Klds) ----
        floatx4 s0 = (floatx4){0.f,0.f,0.f,0.f}, s1 = (floatx4){0.f,0.f,0.f,0.f};
        __builtin_amdgcn_s_setprio(1);
#pragma unroll
        for (int ks = 0; ks < 16; ++ks) {
            bf16x8 k0 = *(const bf16x8*)(Klds + (((ks * 4 + quad) * 32) + c) * 8);
            bf16x8 k1 = *(const bf16x8*)(Klds + (((ks * 4 + quad) * 32) + c + 16) * 8);
            s0 = mfma16(qf[ks], k0, s0);
            s1 = mfma16(qf[ks], k1, s1);
        }
        __builtin_amdgcn_s_setprio(0);
        // ---- no-max softmax: p = exp(s), accumulate l per-lane ----
#pragma unroll
        for (int r = 0; r < 4; ++r) {
            float p0 = __expf(s0[r]);
            float p1 = __expf(s1[r]);
            l_r[r] += p0 + p1;
            int row = w * 16 + quad * 4 + r;
            Plds[row * 40 + c]      = (__bf16)p0;
            Plds[row * 40 + c + 16] = (__bf16)p1;
        }
        __syncthreads();   // A: P visible; V(kt) drained; Klds reads done
        // issue K(kt+1): latency covered by PV phase
        int kn = (kt < 63) ? kt + 1 : 63;
        stage_K(kbase, h * 2048 + kn * 32, Klds, w, lane);
        // ---- O += P V (channel-split: all 64 rows, chans w*128..) ----
        bf16x8 pf[4];
#pragma unroll
        for (int mg = 0; mg < 4; ++mg)
            pf[mg] = *(const bf16x8*)(Plds + (mg * 16 + c) * 40 + quad * 8);
        __builtin_amdgcn_s_setprio(1);
#pragma unroll
        for (int t = 0; t < 8; ++t) {
            bf16x8 vf = *(const bf16x8*)(Vlds + ((size_t)quad * 512 + w * 128 + t * 16 + c) * 8);
#pragma unroll
            for (int mg = 0; mg < 4; ++mg)
                o[mg][t] = mfma16(pf[mg], vf, o[mg][t]);
        }
        __builtin_amdgcn_s_setprio(0);
        __syncthreads();   // C: PV reads done; K(kt+1) drained
    }
    // ---- epilogue: reduce l across the 16 lanes sharing each row ----
#pragma unroll
    for (int r = 0; r < 4; ++r) {
        float l = l_r[r];
        l += __shfl_xor(l, 1);
        l += __shfl_xor(l, 2);
        l += __shfl_xor(l, 4);
        l += __shfl_xor(l, 8);
        l_r[r] = l;
    }
    if (c == 0) {
#pragma unroll
        for (int r = 0; r < 4; ++r) {
            int grow = b * SPB + qt * 64 + w * 16 + quad * 4 + r;
            lpart[h * MTOT + grow] = l_r[r];
        }
    }
    __bf16* ob = h ? op1 : op0;
#pragma unroll
    for (int mg = 0; mg < 4; ++mg)
#pragma unroll
        for (int t = 0; t < 8; ++t)
#pragma unroll
            for (int r = 0; r < 4; ++r) {
                int grow = b * SPB + qt * 64 + mg * 16 + quad * 4 + r;
                ob[(size_t)grow * C_DIM + w * 128 + t * 16 + c] = (__bf16)o[mg][t][r];
            }
}

// ---------------------------------------------------------------------------
// Combine key-half partials: attn = (O0 + O1) / (l0 + l1)
// ---------------------------------------------------------------------------
__global__ __launch_bounds__(256) void combine_kernel(
    const __bf16* __restrict__ o0, const __bf16* __restrict__ o1,
    const float* __restrict__ lpart, __bf16* __restrict__ attn) {
    int tid = threadIdx.x, lane = tid & 63, w = tid >> 6;
    int rbase = blockIdx.x * 64 + w * 16;
    for (int rr = 0; rr < 16; ++rr) {
        int row = rbase + rr;
        float inv = 1.f / (lpart[row] + lpart[MTOT + row]);
        bf16x8 v0 = *(const bf16x8*)(o0 + (size_t)row * C_DIM + lane * 8);
        bf16x8 v1 = *(const bf16x8*)(o1 + (size_t)row * C_DIM + lane * 8);
        bf16x8 r;
#pragma unroll
        for (int j = 0; j < 8; ++j) r[j] = (__bf16)(((float)v0[j] + (float)v1[j]) * inv);
        *(bf16x8*)(attn + (size_t)row * C_DIM + lane * 8) = r;
    }
}

// ---------------------------------------------------------------------------
// out = x + attn @ wo + bo (fp32 output)
// ---------------------------------------------------------------------------
__global__ __launch_bounds__(256, 2) void proj_out(
    const __bf16* __restrict__ attn, const __bf16* __restrict__ wot,
    const float* __restrict__ bo, const float* __restrict__ x,
    float* __restrict__ out) {
    __shared__ __bf16 Alds[128 * 32];
    __shared__ __bf16 Blds[128 * 32];
    int tid = threadIdx.x, lane = tid & 63, w = tid >> 6;
    int c = lane & 15, quad = lane >> 4;
    int wm = w & 1, wn = w >> 1;
    int mbase = blockIdx.x * 128, nbase = blockIdx.y * 128;
    floatx4 acc[4][4] = {};
    for (int kb = 0; kb < 16; ++kb) {
        __syncthreads();
#pragma unroll
        for (int p = 0; p < 2; ++p) {
            int chunk0 = w * 128 + p * 64;
            int chunk = chunk0 + lane;
            int row = chunk >> 2, qk = chunk & 3;
            gload16(attn + (size_t)(mbase + row) * C_DIM + kb * 32 + qk * 8, Alds + chunk0 * 8);
            gload16(wot + (size_t)(nbase + row) * C_DIM + kb * 32 + qk * 8, Blds + chunk0 * 8);
        }
        __syncthreads();
        bf16x8 af[4], bfr[4];
#pragma unroll
        for (int mt = 0; mt < 4; ++mt)
            af[mt] = *(const bf16x8*)(Alds + (wm * 64 + mt * 16 + c) * 32 + quad * 8);
#pragma unroll
        for (int nt = 0; nt < 4; ++nt)
            bfr[nt] = *(const bf16x8*)(Blds + (wn * 64 + nt * 16 + c) * 32 + quad * 8);
#pragma unroll
        for (int mt = 0; mt < 4; ++mt)
#pragma unroll
            for (int nt = 0; nt < 4; ++nt)
                acc[mt][nt] = mfma16(af[mt], bfr[nt], acc[mt][nt]);
    }
#pragma unroll
    for (int nt = 0; nt < 4; ++nt) {
        int n = nbase + wn * 64 + nt * 16 + c;
        float bval = bo[n];
#pragma unroll
        for (int mt = 0; mt < 4; ++mt) {
            int m0 = mbase + wm * 64 + mt * 16 + quad * 4;
#pragma unroll
            for (int r = 0; r < 4; ++r) {
                size_t idx = (size_t)(m0 + r) * C_DIM + n;
                out[idx] = acc[mt][nt][r] + bval + x[idx];
            }
        }
    }
}

// ---------------------------------------------------------------------------
extern "C" void kernel_launch(void* const* d_in, const int* in_sizes, int n_in,
                              void* d_out, int out_size, void* d_ws, size_t ws_size,
                              hipStream_t stream) {
    const float* x   = (const float*)d_in[0];
    const float* gsc = (const float*)d_in[1];
    const float* gbi = (const float*)d_in[2];
    const float* wq  = (const float*)d_in[3];
    const float* bq  = (const float*)d_in[4];
    const float* wk  = (const float*)d_in[5];
    const float* bk  = (const float*)d_in[6];
    const float* wv  = (const float*)d_in[7];
    const float* bv  = (const float*)d_in[8];
    const float* wo  = (const float*)d_in[9];
    const float* bo  = (const float*)d_in[10];
    char* ws = (char*)d_ws;
    __bf16* hn  = (__bf16*)(ws + HN_OFF);
    __bf16* qb  = (__bf16*)(ws + Q_OFF);
    __bf16* kb  = (__bf16*)(ws + K_OFF);
    __bf16* v4  = (__bf16*)(ws + V4_OFF);
    __bf16* wt  = (__bf16*)(ws + WT_OFF);
    __bf16* op0 = (__bf16*)(ws + HN_OFF);   // hn dead during flash
    __bf16* op1 = (__bf16*)(ws + O1_OFF);
    float*  lp  = (float*)(ws + ML_OFF);
    float*  gs  = (float*)(ws + GS_OFF);
    __bf16* attn = qb;                      // q dead after flash
    float* out = (float*)d_out;

    zero_stats<<<1, 256, 0, stream>>>(gs);
    wt_kernel<<<dim3(16, 16, 4), 256, 0, stream>>>(wq, wk, wv, wo, wt);
    gn_stats<<<dim3(128, 4), 256, 0, stream>>>(x, gs);
    gn_apply<<<dim3(128, 4), 256, 0, stream>>>(x, gs, gsc, gbi, hn);
    proj_qkv<<<dim3(128, 4, 3), 256, 0, stream>>>(hn, wt, bq, bk, bv, qb, kb, v4);
    flash_kernel<<<512, 256, 0, stream>>>(qb, kb, v4, op0, op1, lp);
    combine_kernel<<<256, 256, 0, stream>>>(op0, op1, lp, attn);
    proj_out<<<dim3(128, 4), 256, 0, stream>>>(attn, wt + (size_t)3 * C_DIM * C_DIM, bo, x, out);
}